// Round 2
// baseline (584.439 us; speedup 1.0000x reference)
//
#include <hip/hip_runtime.h>

// NCC dual-force 3D, 256^3 fp32.
// One wave spans the FULL x-row: 64 lanes x 4 floats (float4) = 256.
// Separable 3x3x3 box sums: y-sum in registers, x-sum via 2 shuffles per
// quantity, z-sum via pair-sum accumulators (SA=P[z-2]+P[z-1], SB=P[z-1] —
// bit-identical association to the old add3 ring, 20 fewer VGPRs).
// R5: explicit 1-iteration software prefetch — plane s+1 raw rows and
// output zo+1 masks are issued mid-iteration s and consumed a full
// iteration later (~600+ cyc distance), so NT-mask/HBM latency hides under
// the ingest+pw1 compute instead of stalling every step (R4: VALUBusy 43%,
// hbm 41%, dur 133us = 2x the 68us HBM floor -> latency-bound).
// FP op order is UNCHANGED from R1/R4 (absmax must stay exactly 80).
// (R5 resubmit: previous bench was GPUAcquisitionTimeout, no data.)

constexpr int DIM     = 256;
constexpr int PLANE   = DIM * DIM;
constexpr int NVOX    = DIM * DIM * DIM;
constexpr int CHUNK_Z = 8;             // outputs per thread along z
constexpr int BY      = 2;             // waves per block (y rows)
constexpr float EPSF  = 1e-6f;

// native vector types for nontemporal builtins (HIP_vector_type is rejected)
typedef float nvec4 __attribute__((ext_vector_type(4)));
typedef int   nivec4 __attribute__((ext_vector_type(4)));

__device__ __forceinline__ float shlz(float v) {   // lane l <- lane l-1; lane0 -> 0 (zero pad)
    float r = __shfl_up(v, 1);
    return (threadIdx.x == 0) ? 0.f : r;
}
__device__ __forceinline__ float shrz(float v) {   // lane l <- lane l+1; lane63 -> 0
    float r = __shfl_down(v, 1);
    return (threadIdx.x == 63) ? 0.f : r;
}
__device__ __forceinline__ float4 add3(const float4& a, const float4& b, const float4& c) {
    return make_float4(a.x+b.x+c.x, a.y+b.y+c.y, a.z+b.z+c.z, a.w+b.w+c.w);
}
__device__ __forceinline__ float4 add2(const float4& a, const float4& b) {
    return make_float4(a.x+b.x, a.y+b.y, a.z+b.z, a.w+b.w);
}
__device__ __forceinline__ float4 prod3(const float4& a, const float4& b,
                                        const float4& c, const float4& d,
                                        const float4& e, const float4& f) {
    return make_float4(a.x*b.x + c.x*d.x + e.x*f.x,
                       a.y*b.y + c.y*d.y + e.y*f.y,
                       a.z*b.z + c.z*d.z + e.z*f.z,
                       a.w*b.w + c.w*d.w + e.w*f.w);
}
__device__ __forceinline__ float4 sub4(const float4& a, const float4& b) {
    return make_float4(a.x-b.x, a.y-b.y, a.z-b.z, a.w-b.w);
}
__device__ __forceinline__ float4 scl4(const float4& a, float s) {
    return make_float4(a.x*s, a.y*s, a.z*s, a.w*s);
}
// 3-wide x window sum of a per-element quantity; ends from neighbor lanes (zero-padded)
__device__ __forceinline__ float4 xsum3(const float4& c) {
    float l = shlz(c.w), r = shrz(c.x);
    return make_float4(l + c.x + c.y, c.x + c.y + c.z, c.y + c.z + c.w, c.z + c.w + r);
}
__device__ __forceinline__ void ntstore4(float* p, const float4& v) {
    nvec4 t; t.x = v.x; t.y = v.y; t.z = v.z; t.w = v.w;
    __builtin_nontemporal_store(t, (nvec4*)p);
}

// scalar pointwise NCC-force; arithmetic replicates the reference (and the
// R1 kernel, absmax 56) op-for-op — do NOT reorder, eps-denominator voxels
// are hyper-sensitive (R3's nf=-0.5*factor refactor cost absmax 56->80).
__device__ __forceinline__ void pw1(
    float sum_m, float sum_f, float sum_mm, float sum_ff, float sum_mf,
    float mA, float mB, float mN,   // m at planes zo-1, zo, zo+1
    float fA, float fB, float fN,
    int zflag,                      // -1: zo==0, +1: zo==DIM-1, 0: interior
    float gx_m, float gy_m, float gx_f, float gy_f,
    int km, int kf,
    float& o0, float& o1, float& o2)
{
    float mmean = sum_m / 27.0f;
    float fmean = sum_f / 27.0f;
    float var_m = sum_mm - 2.f*mmean*sum_m + 27.f*mmean*mmean;
    float var_f = sum_ff - 2.f*fmean*sum_f + 27.f*fmean*fmean;
    float var_mf = var_m * var_f;
    float cross = sum_mf - fmean*sum_m - mmean*sum_f + 27.f*mmean*fmean;
    float mmc = mB - mmean, fmc = fB - fmean;
    float factor = 2.f * cross / (var_mf + EPSF)
                   * (mmc - cross / (var_f*fmc + EPSF));
    float gzm = (zflag < 0) ? (mN - mB) : ((zflag > 0) ? (mB - mA) : 0.5f*(mN - mA));
    float gzf = (zflag < 0) ? (fN - fB) : ((zflag > 0) ? (fB - fA) : 0.5f*(fN - fA));
    float wm = km ? 1.f : 0.f, wf = kf ? 1.f : 0.f;
    float tgz = 0.5f*(gzm *wm + gzf *wf);
    float tgy = 0.5f*(gy_m*wm + gy_f*wf);
    float tgx = 0.5f*(gx_m*wm + gx_f*wf);
    o0 = -factor * tgz;
    o1 = -factor * tgy;
    o2 = -factor * tgx;
}

// raw rows of one z-plane for this wave's y (3 m-rows + 3 f-rows)
struct RawP { float4 mU, mC, mD, fU, fC, fD; };

__device__ __forceinline__ RawP load_planes(const float* __restrict__ M,
                                            const float* __restrict__ F,
                                            int zl, size_t yoff, bool yUok, bool yDok)
{
    const float4 z4 = make_float4(0.f, 0.f, 0.f, 0.f);
    RawP r; r.mU = z4; r.mC = z4; r.mD = z4; r.fU = z4; r.fC = z4; r.fD = z4;
    if ((unsigned)zl < (unsigned)DIM) {
        const float* pm = M + (size_t)zl * PLANE + yoff;
        const float* pf = F + (size_t)zl * PLANE + yoff;
        r.mC = *(const float4*)pm;  r.fC = *(const float4*)pf;
        if (yUok) { r.mU = *(const float4*)(pm - DIM); r.fU = *(const float4*)(pf - DIM); }
        if (yDok) { r.mD = *(const float4*)(pm + DIM); r.fD = *(const float4*)(pf + DIM); }
    }
    return r;
}

// pure compute half of the old 'ingest' — FP statements in identical order
__device__ __forceinline__ void ingest_compute(
    const RawP& r, int slot, int y,
    float4* mc, float4* fc,
    float4& Pm, float4& Pf, float4& Pmm, float4& Pff, float4& Pmf,
    float4& gxm, float4& gym, float4& gxf, float4& gyf)
{
    const float4 mU = r.mU, mC = r.mC, mD = r.mD;
    const float4 fU = r.fU, fC = r.fC, fD = r.fD;
    // y-sums per element (zero-padded SAME)
    float4 Cm  = add3(mU, mC, mD);
    float4 Cf  = add3(fU, fC, fD);
    float4 Cmm = prod3(mU, mU, mC, mC, mD, mD);
    float4 Cff = prod3(fU, fU, fC, fC, fD, fD);
    float4 Cmf = prod3(mU, fU, mC, fC, mD, fD);
    // x-sums (2 shuffles each)
    Pm  = xsum3(Cm);
    Pf  = xsum3(Cf);
    Pmm = xsum3(Cmm);
    Pff = xsum3(Cff);
    Pmf = xsum3(Cmf);
    mc[slot] = mC; fc[slot] = fC;
    // in-plane gradients at this plane (torch.gradient boundary rules)
    float mL = shlz(mC.w), mR = shrz(mC.x);
    float fL = shlz(fC.w), fR = shrz(fC.x);
    gxm = make_float4((threadIdx.x == 0)  ? (mC.y - mC.x) : 0.5f*(mC.y - mL),
                      0.5f*(mC.z - mC.x),
                      0.5f*(mC.w - mC.y),
                      (threadIdx.x == 63) ? (mC.w - mC.z) : 0.5f*(mR - mC.z));
    gxf = make_float4((threadIdx.x == 0)  ? (fC.y - fC.x) : 0.5f*(fC.y - fL),
                      0.5f*(fC.z - fC.x),
                      0.5f*(fC.w - fC.y),
                      (threadIdx.x == 63) ? (fC.w - fC.z) : 0.5f*(fR - fC.z));
    gym = (y == 0) ? sub4(mD, mC) : (y == DIM-1) ? sub4(mC, mU) : scl4(sub4(mD, mU), 0.5f);
    gyf = (y == 0) ? sub4(fD, fC) : (y == DIM-1) ? sub4(fC, fU) : scl4(sub4(fD, fU), 0.5f);
}

__global__ __launch_bounds__(64 * BY, 4) void ncc_forces(
    const float* __restrict__ M, const float* __restrict__ F,
    const int* __restrict__ maskM, const int* __restrict__ maskF,
    float* __restrict__ out)
{
    const int y  = blockIdx.y * BY + threadIdx.y;
    const int z0 = blockIdx.z * CHUNK_Z;
    const int xb = threadIdx.x * 4;
    const bool yUok = (y > 0), yDok = (y < DIM - 1);
    const size_t yoff = (size_t)y * DIM + xb;

    float4 mc[3], fc[3];                 // center values z-ring
    float4 gxm_p, gym_p, gxf_p, gyf_p;   // in-plane grads at output plane

    // ---- prologue: issue everything before the first compute ----
    // masks for first output (zo = z0); consumed at s=2 (covered by 2 ingests)
    nivec4 km = __builtin_nontemporal_load((const nivec4*)(maskM + (size_t)z0 * PLANE + yoff));
    nivec4 kf = __builtin_nontemporal_load((const nivec4*)(maskF + (size_t)z0 * PLANE + yoff));
    RawP r0 = load_planes(M, F, z0 - 1, yoff, yUok, yDok);
    RawP r1 = load_planes(M, F, z0,     yoff, yUok, yDok);
    RawP rN = load_planes(M, F, z0 + 1, yoff, yUok, yDok);   // consumed at s=2

    // pair-sum z-accumulators: SA = P(old)+P(mid), SB = P(mid)
    float4 SAm, SAf, SAmm, SAff, SAmf, SBm, SBf, SBmm, SBff, SBmf;
    {
        float4 P0m, P0f, P0mm, P0ff, P0mf, d0, d1, d2, d3;
        ingest_compute(r0, 0, y, mc, fc, P0m, P0f, P0mm, P0ff, P0mf, d0, d1, d2, d3);
        float4 P1m, P1f, P1mm, P1ff, P1mf;
        ingest_compute(r1, 1, y, mc, fc, P1m, P1f, P1mm, P1ff, P1mf,
                       gxm_p, gym_p, gxf_p, gyf_p);
        // (P0+P1) — same association as add3's (a+b)+c first add
        SAm  = add2(P0m,  P1m );  SBm  = P1m;
        SAf  = add2(P0f,  P1f );  SBf  = P1f;
        SAmm = add2(P0mm, P1mm);  SBmm = P1mm;
        SAff = add2(P0ff, P1ff);  SBff = P1ff;
        SAmf = add2(P0mf, P1mf);  SBmf = P1mf;
    }

    #pragma unroll
    for (int s = 2; s < CHUNK_Z + 2; ++s) {
        const int i2 = s % 3, i1 = (s + 2) % 3, i0 = (s + 1) % 3;
        const int zo = z0 + s - 2;
        const int zflag = (zo == 0) ? -1 : ((zo == DIM - 1) ? 1 : 0);
        const size_t idx = (size_t)zo * PLANE + yoff;

        // 1) consume the raw loads issued one iteration ago
        float4 gxm, gym, gxf, gyf;
        float4 Pm2, Pf2, Pmm2, Pff2, Pmf2;
        ingest_compute(rN, i2, y, mc, fc, Pm2, Pf2, Pmm2, Pff2, Pmf2,
                       gxm, gym, gxf, gyf);

        // 2) issue NEXT plane's raw rows and NEXT output's masks now;
        //    they are consumed one iteration later (~a full ingest+pw1 of cover)
        nivec4 kmT, kfT;
        if (s < CHUNK_Z + 1) {
            rN  = load_planes(M, F, z0 + s, yoff, yUok, yDok);     // plane for s+1
            kmT = __builtin_nontemporal_load((const nivec4*)(maskM + idx + PLANE));
            kfT = __builtin_nontemporal_load((const nivec4*)(maskF + idx + PLANE));
        }

        // 3) z-sums: (P[z-2]+P[z-1]) + P[z] — identical association to add3
        float4 sm  = add2(SAm,  Pm2);
        float4 sf  = add2(SAf,  Pf2);
        float4 smm = add2(SAmm, Pmm2);
        float4 sff = add2(SAff, Pff2);
        float4 smf = add2(SAmf, Pmf2);

        float4 o0, o1, o2;
        pw1(sm.x, sf.x, smm.x, sff.x, smf.x, mc[i0].x, mc[i1].x, mc[i2].x,
            fc[i0].x, fc[i1].x, fc[i2].x, zflag, gxm_p.x, gym_p.x, gxf_p.x, gyf_p.x,
            km.x, kf.x, o0.x, o1.x, o2.x);
        pw1(sm.y, sf.y, smm.y, sff.y, smf.y, mc[i0].y, mc[i1].y, mc[i2].y,
            fc[i0].y, fc[i1].y, fc[i2].y, zflag, gxm_p.y, gym_p.y, gxf_p.y, gyf_p.y,
            km.y, kf.y, o0.y, o1.y, o2.y);
        pw1(sm.z, sf.z, smm.z, sff.z, smf.z, mc[i0].z, mc[i1].z, mc[i2].z,
            fc[i0].z, fc[i1].z, fc[i2].z, zflag, gxm_p.z, gym_p.z, gxf_p.z, gyf_p.z,
            km.z, kf.z, o0.z, o1.z, o2.z);
        pw1(sm.w, sf.w, smm.w, sff.w, smf.w, mc[i0].w, mc[i1].w, mc[i2].w,
            fc[i0].w, fc[i1].w, fc[i2].w, zflag, gxm_p.w, gym_p.w, gxf_p.w, gyf_p.w,
            km.w, kf.w, o0.w, o1.w, o2.w);

        ntstore4(out + idx,            o0);   // channel 0: d/dz
        ntstore4(out + NVOX + idx,     o1);   // channel 1: d/dy
        ntstore4(out + 2 * NVOX + idx, o2);   // channel 2: d/dx

        // 4) rotate accumulators / prefetch buffers
        SAm  = add2(SBm,  Pm2 );  SBm  = Pm2;
        SAf  = add2(SBf,  Pf2 );  SBf  = Pf2;
        SAmm = add2(SBmm, Pmm2);  SBmm = Pmm2;
        SAff = add2(SBff, Pff2);  SBff = Pff2;
        SAmf = add2(SBmf, Pmf2);  SBmf = Pmf2;
        gxm_p = gxm; gym_p = gym; gxf_p = gxf; gyf_p = gyf;
        if (s < CHUNK_Z + 1) { km = kmT; kf = kfT; }
    }
}

extern "C" void kernel_launch(void* const* d_in, const int* in_sizes, int n_in,
                              void* d_out, int out_size, void* d_ws, size_t ws_size,
                              hipStream_t stream) {
    const float* M  = (const float*)d_in[0];
    const float* F  = (const float*)d_in[1];
    const int* mm   = (const int*)d_in[2];
    const int* fm   = (const int*)d_in[3];
    float* out      = (float*)d_out;

    dim3 block(64, BY, 1);                       // one wave = one full x-row
    dim3 grid(1, DIM / BY, DIM / CHUNK_Z);       // 1 x 128 x 32 = 4096 blocks
    hipLaunchKernelGGL(ncc_forces, grid, block, 0, stream, M, F, mm, fm, out);
}

// Round 3
// 379.111 us; speedup vs baseline: 1.5416x; 1.5416x over previous
//
#include <hip/hip_runtime.h>

// NCC dual-force 3D, 256^3 fp32.
// One wave spans the FULL x-row: 64 lanes x 4 floats (float4) = 256.
// Separable 3x3x3 box sums: y-sum in registers, x-sum via 2 shuffles per
// quantity, z-sum via a 3-deep register ring (compile-time rotation under
// full unroll). 4 outputs per lane per plane-step. No LDS, no syncthreads.
// R6: exact R4 structure (R5's prefetch + __launch_bounds__(128,4) forced a
// 64-VGPR budget -> ~880MB scratch spill traffic, 2.6x regression).
// Only change vs R4: NT mask loads are issued ONE ITERATION EARLY (+8 VGPR,
// stays in the 4-waves/SIMD step), so the ~900cy HBM mask latency hides
// under a full ingest+pw1 instead of stalling pw1 every step.
// FP op order is UNCHANGED from R1/R4 (absmax must stay exactly 80).

constexpr int DIM     = 256;
constexpr int PLANE   = DIM * DIM;
constexpr int NVOX    = DIM * DIM * DIM;
constexpr int CHUNK_Z = 8;             // outputs per thread along z
constexpr int BY      = 2;             // waves per block (y rows)
constexpr float EPSF  = 1e-6f;

// native vector types for nontemporal builtins (HIP_vector_type is rejected)
typedef float nvec4 __attribute__((ext_vector_type(4)));
typedef int   nivec4 __attribute__((ext_vector_type(4)));

__device__ __forceinline__ float shlz(float v) {   // lane l <- lane l-1; lane0 -> 0 (zero pad)
    float r = __shfl_up(v, 1);
    return (threadIdx.x == 0) ? 0.f : r;
}
__device__ __forceinline__ float shrz(float v) {   // lane l <- lane l+1; lane63 -> 0
    float r = __shfl_down(v, 1);
    return (threadIdx.x == 63) ? 0.f : r;
}
__device__ __forceinline__ float4 add3(const float4& a, const float4& b, const float4& c) {
    return make_float4(a.x+b.x+c.x, a.y+b.y+c.y, a.z+b.z+c.z, a.w+b.w+c.w);
}
__device__ __forceinline__ float4 prod3(const float4& a, const float4& b,
                                        const float4& c, const float4& d,
                                        const float4& e, const float4& f) {
    return make_float4(a.x*b.x + c.x*d.x + e.x*f.x,
                       a.y*b.y + c.y*d.y + e.y*f.y,
                       a.z*b.z + c.z*d.z + e.z*f.z,
                       a.w*b.w + c.w*d.w + e.w*f.w);
}
__device__ __forceinline__ float4 sub4(const float4& a, const float4& b) {
    return make_float4(a.x-b.x, a.y-b.y, a.z-b.z, a.w-b.w);
}
__device__ __forceinline__ float4 scl4(const float4& a, float s) {
    return make_float4(a.x*s, a.y*s, a.z*s, a.w*s);
}
// 3-wide x window sum of a per-element quantity; ends from neighbor lanes (zero-padded)
__device__ __forceinline__ float4 xsum3(const float4& c) {
    float l = shlz(c.w), r = shrz(c.x);
    return make_float4(l + c.x + c.y, c.x + c.y + c.z, c.y + c.z + c.w, c.z + c.w + r);
}
__device__ __forceinline__ void ntstore4(float* p, const float4& v) {
    nvec4 t; t.x = v.x; t.y = v.y; t.z = v.z; t.w = v.w;
    __builtin_nontemporal_store(t, (nvec4*)p);
}

// scalar pointwise NCC-force; arithmetic replicates the reference (and the
// R1 kernel, absmax 56) op-for-op — do NOT reorder, eps-denominator voxels
// are hyper-sensitive (R3's nf=-0.5*factor refactor cost absmax 56->80).
__device__ __forceinline__ void pw1(
    float sum_m, float sum_f, float sum_mm, float sum_ff, float sum_mf,
    float mA, float mB, float mN,   // m at planes zo-1, zo, zo+1
    float fA, float fB, float fN,
    int zflag,                      // -1: zo==0, +1: zo==DIM-1, 0: interior
    float gx_m, float gy_m, float gx_f, float gy_f,
    int km, int kf,
    float& o0, float& o1, float& o2)
{
    float mmean = sum_m / 27.0f;
    float fmean = sum_f / 27.0f;
    float var_m = sum_mm - 2.f*mmean*sum_m + 27.f*mmean*mmean;
    float var_f = sum_ff - 2.f*fmean*sum_f + 27.f*fmean*fmean;
    float var_mf = var_m * var_f;
    float cross = sum_mf - fmean*sum_m - mmean*sum_f + 27.f*mmean*fmean;
    float mmc = mB - mmean, fmc = fB - fmean;
    float factor = 2.f * cross / (var_mf + EPSF)
                   * (mmc - cross / (var_f*fmc + EPSF));
    float gzm = (zflag < 0) ? (mN - mB) : ((zflag > 0) ? (mB - mA) : 0.5f*(mN - mA));
    float gzf = (zflag < 0) ? (fN - fB) : ((zflag > 0) ? (fB - fA) : 0.5f*(fN - fA));
    float wm = km ? 1.f : 0.f, wf = kf ? 1.f : 0.f;
    float tgz = 0.5f*(gzm *wm + gzf *wf);
    float tgy = 0.5f*(gy_m*wm + gy_f*wf);
    float tgx = 0.5f*(gx_m*wm + gx_f*wf);
    o0 = -factor * tgz;
    o1 = -factor * tgy;
    o2 = -factor * tgx;
}

__global__ __launch_bounds__(64 * BY) void ncc_forces(
    const float* __restrict__ M, const float* __restrict__ F,
    const int* __restrict__ maskM, const int* __restrict__ maskF,
    float* __restrict__ out)
{
    const int y  = blockIdx.y * BY + threadIdx.y;
    const int z0 = blockIdx.z * CHUNK_Z;
    const int xb = threadIdx.x * 4;
    const bool yUok = (y > 0), yDok = (y < DIM - 1);
    const size_t yoff = (size_t)y * DIM + xb;

    float4 Pm[3], Pf[3], Pmm[3], Pff[3], Pmf[3];   // plane-sum z-ring
    float4 mc[3], fc[3];                           // center values z-ring
    float4 gxm_p, gym_p, gxf_p, gyf_p;             // in-plane grads at plane zo

    auto ingest = [&](int slot, int zl, float4& gxm, float4& gym, float4& gxf, float4& gyf) {
        const float4 z4 = make_float4(0.f, 0.f, 0.f, 0.f);
        float4 mU = z4, mC = z4, mD = z4, fU = z4, fC = z4, fD = z4;
        if ((unsigned)zl < (unsigned)DIM) {
            const float* pm = M + (size_t)zl * PLANE + yoff;
            const float* pf = F + (size_t)zl * PLANE + yoff;
            mC = *(const float4*)pm;  fC = *(const float4*)pf;
            if (yUok) { mU = *(const float4*)(pm - DIM); fU = *(const float4*)(pf - DIM); }
            if (yDok) { mD = *(const float4*)(pm + DIM); fD = *(const float4*)(pf + DIM); }
        }
        // y-sums per element (zero-padded SAME)
        float4 Cm  = add3(mU, mC, mD);
        float4 Cf  = add3(fU, fC, fD);
        float4 Cmm = prod3(mU, mU, mC, mC, mD, mD);
        float4 Cff = prod3(fU, fU, fC, fC, fD, fD);
        float4 Cmf = prod3(mU, fU, mC, fC, mD, fD);
        // x-sums (2 shuffles each)
        Pm[slot]  = xsum3(Cm);
        Pf[slot]  = xsum3(Cf);
        Pmm[slot] = xsum3(Cmm);
        Pff[slot] = xsum3(Cff);
        Pmf[slot] = xsum3(Cmf);
        mc[slot] = mC; fc[slot] = fC;
        // in-plane gradients at plane zl (torch.gradient boundary rules)
        float mL = shlz(mC.w), mR = shrz(mC.x);
        float fL = shlz(fC.w), fR = shrz(fC.x);
        gxm = make_float4((threadIdx.x == 0)  ? (mC.y - mC.x) : 0.5f*(mC.y - mL),
                          0.5f*(mC.z - mC.x),
                          0.5f*(mC.w - mC.y),
                          (threadIdx.x == 63) ? (mC.w - mC.z) : 0.5f*(mR - mC.z));
        gxf = make_float4((threadIdx.x == 0)  ? (fC.y - fC.x) : 0.5f*(fC.y - fL),
                          0.5f*(fC.z - fC.x),
                          0.5f*(fC.w - fC.y),
                          (threadIdx.x == 63) ? (fC.w - fC.z) : 0.5f*(fR - fC.z));
        gym = (y == 0) ? sub4(mD, mC) : (y == DIM-1) ? sub4(mC, mU) : scl4(sub4(mD, mU), 0.5f);
        gyf = (y == 0) ? sub4(fD, fC) : (y == DIM-1) ? sub4(fC, fU) : scl4(sub4(fD, fU), 0.5f);
    };

    // ---- prologue ----
    // masks for the FIRST output plane (zo = z0): issued before the two
    // priming ingests, so they have ~2 ingests of compute to land under.
    nivec4 km = __builtin_nontemporal_load((const nivec4*)(maskM + (size_t)z0 * PLANE + yoff));
    nivec4 kf = __builtin_nontemporal_load((const nivec4*)(maskF + (size_t)z0 * PLANE + yoff));

    // prime ring: planes z0-1 (zero pad if z0==0) and z0
    { float4 d0, d1, d2, d3; ingest(0, z0 - 1, d0, d1, d2, d3); }
    ingest(1, z0, gxm_p, gym_p, gxf_p, gyf_p);

    #pragma unroll
    for (int s = 2; s < CHUNK_Z + 2; ++s) {
        const int i2 = s % 3, i1 = (s + 2) % 3, i0 = (s + 1) % 3;
        float4 gxm, gym, gxf, gyf;
        ingest(i2, z0 - 1 + s, gxm, gym, gxf, gyf);

        const int zo = z0 + s - 2;
        const int zflag = (zo == 0) ? -1 : ((zo == DIM - 1) ? 1 : 0);
        const size_t idx = (size_t)zo * PLANE + yoff;

        // prefetch NEXT output's masks now; consumed one iteration later
        // (covered by a full ingest + pw1 ≈ 600+ cycles of compute).
        // s is a compile-time constant under full unroll -> no divergence.
        nivec4 kmT, kfT;
        if (s < CHUNK_Z + 1) {
            kmT = __builtin_nontemporal_load((const nivec4*)(maskM + idx + PLANE));
            kfT = __builtin_nontemporal_load((const nivec4*)(maskF + idx + PLANE));
        }

        float4 sm  = add3(Pm[i0],  Pm[i1],  Pm[i2]);
        float4 sf  = add3(Pf[i0],  Pf[i1],  Pf[i2]);
        float4 smm = add3(Pmm[i0], Pmm[i1], Pmm[i2]);
        float4 sff = add3(Pff[i0], Pff[i1], Pff[i2]);
        float4 smf = add3(Pmf[i0], Pmf[i1], Pmf[i2]);

        float4 o0, o1, o2;
        pw1(sm.x, sf.x, smm.x, sff.x, smf.x, mc[i0].x, mc[i1].x, mc[i2].x,
            fc[i0].x, fc[i1].x, fc[i2].x, zflag, gxm_p.x, gym_p.x, gxf_p.x, gyf_p.x,
            km.x, kf.x, o0.x, o1.x, o2.x);
        pw1(sm.y, sf.y, smm.y, sff.y, smf.y, mc[i0].y, mc[i1].y, mc[i2].y,
            fc[i0].y, fc[i1].y, fc[i2].y, zflag, gxm_p.y, gym_p.y, gxf_p.y, gyf_p.y,
            km.y, kf.y, o0.y, o1.y, o2.y);
        pw1(sm.z, sf.z, smm.z, sff.z, smf.z, mc[i0].z, mc[i1].z, mc[i2].z,
            fc[i0].z, fc[i1].z, fc[i2].z, zflag, gxm_p.z, gym_p.z, gxf_p.z, gyf_p.z,
            km.z, kf.z, o0.z, o1.z, o2.z);
        pw1(sm.w, sf.w, smm.w, sff.w, smf.w, mc[i0].w, mc[i1].w, mc[i2].w,
            fc[i0].w, fc[i1].w, fc[i2].w, zflag, gxm_p.w, gym_p.w, gxf_p.w, gyf_p.w,
            km.w, kf.w, o0.w, o1.w, o2.w);

        ntstore4(out + idx,            o0);   // channel 0: d/dz
        ntstore4(out + NVOX + idx,     o1);   // channel 1: d/dy
        ntstore4(out + 2 * NVOX + idx, o2);   // channel 2: d/dx

        gxm_p = gxm; gym_p = gym; gxf_p = gxf; gyf_p = gyf;
        if (s < CHUNK_Z + 1) { km = kmT; kf = kfT; }
    }
}

extern "C" void kernel_launch(void* const* d_in, const int* in_sizes, int n_in,
                              void* d_out, int out_size, void* d_ws, size_t ws_size,
                              hipStream_t stream) {
    const float* M  = (const float*)d_in[0];
    const float* F  = (const float*)d_in[1];
    const int* mm   = (const int*)d_in[2];
    const int* fm   = (const int*)d_in[3];
    float* out      = (float*)d_out;

    dim3 block(64, BY, 1);                       // one wave = one full x-row
    dim3 grid(1, DIM / BY, DIM / CHUNK_Z);       // 1 x 128 x 32 = 4096 blocks
    hipLaunchKernelGGL(ncc_forces, grid, block, 0, stream, M, F, mm, fm, out);
}

// Round 5
// 375.358 us; speedup vs baseline: 1.5570x; 1.0100x over previous
//
#include <hip/hip_runtime.h>

// NCC dual-force 3D, 256^3 fp32.
// One wave spans the FULL x-row: 64 lanes x 4 floats (float4) = 256.
// Separable 3x3x3 box sums: y-sum in registers, x-sum via 2 shuffles per
// quantity, z-sum via pair-sum accumulators (SA=P[z-2]+P[z-1], SB=P[z-1] —
// bit-identical association to the add3 ring, ~20 fewer VGPRs).
// R7: R5's 1-iteration software prefetch (plane s+1 rows + masks issued
// mid-iteration s, consumed a full ingest+pw1 later) but WITHOUT the
// min-waves launch_bounds arg. R5's 2.6x regression was __launch_bounds__
// (128,4) forcing a 64-VGPR budget -> ~880MB scratch traffic (VGPR=64,
// WRITE 720MB). R6 (same shape, no cap) landed at VGPR=100, zero spill.
// Spill tripwire for this round: WRITE_SIZE must stay ~197MB.
// FP op order is UNCHANGED from R1/R4/R6 (absmax must stay exactly 80).
// (R7 resubmit: previous bench was GPUAcquisitionTimeout, no data.)

constexpr int DIM     = 256;
constexpr int PLANE   = DIM * DIM;
constexpr int NVOX    = DIM * DIM * DIM;
constexpr int CHUNK_Z = 8;             // outputs per thread along z
constexpr int BY      = 2;             // waves per block (y rows)
constexpr float EPSF  = 1e-6f;

// native vector types for nontemporal builtins (HIP_vector_type is rejected)
typedef float nvec4 __attribute__((ext_vector_type(4)));
typedef int   nivec4 __attribute__((ext_vector_type(4)));

__device__ __forceinline__ float shlz(float v) {   // lane l <- lane l-1; lane0 -> 0 (zero pad)
    float r = __shfl_up(v, 1);
    return (threadIdx.x == 0) ? 0.f : r;
}
__device__ __forceinline__ float shrz(float v) {   // lane l <- lane l+1; lane63 -> 0
    float r = __shfl_down(v, 1);
    return (threadIdx.x == 63) ? 0.f : r;
}
__device__ __forceinline__ float4 add3(const float4& a, const float4& b, const float4& c) {
    return make_float4(a.x+b.x+c.x, a.y+b.y+c.y, a.z+b.z+c.z, a.w+b.w+c.w);
}
__device__ __forceinline__ float4 add2(const float4& a, const float4& b) {
    return make_float4(a.x+b.x, a.y+b.y, a.z+b.z, a.w+b.w);
}
__device__ __forceinline__ float4 prod3(const float4& a, const float4& b,
                                        const float4& c, const float4& d,
                                        const float4& e, const float4& f) {
    return make_float4(a.x*b.x + c.x*d.x + e.x*f.x,
                       a.y*b.y + c.y*d.y + e.y*f.y,
                       a.z*b.z + c.z*d.z + e.z*f.z,
                       a.w*b.w + c.w*d.w + e.w*f.w);
}
__device__ __forceinline__ float4 sub4(const float4& a, const float4& b) {
    return make_float4(a.x-b.x, a.y-b.y, a.z-b.z, a.w-b.w);
}
__device__ __forceinline__ float4 scl4(const float4& a, float s) {
    return make_float4(a.x*s, a.y*s, a.z*s, a.w*s);
}
// 3-wide x window sum of a per-element quantity; ends from neighbor lanes (zero-padded)
__device__ __forceinline__ float4 xsum3(const float4& c) {
    float l = shlz(c.w), r = shrz(c.x);
    return make_float4(l + c.x + c.y, c.x + c.y + c.z, c.y + c.z + c.w, c.z + c.w + r);
}
__device__ __forceinline__ void ntstore4(float* p, const float4& v) {
    nvec4 t; t.x = v.x; t.y = v.y; t.z = v.z; t.w = v.w;
    __builtin_nontemporal_store(t, (nvec4*)p);
}

// scalar pointwise NCC-force; arithmetic replicates the reference (and the
// R1 kernel, absmax 56) op-for-op — do NOT reorder, eps-denominator voxels
// are hyper-sensitive (R3's nf=-0.5*factor refactor cost absmax 56->80).
__device__ __forceinline__ void pw1(
    float sum_m, float sum_f, float sum_mm, float sum_ff, float sum_mf,
    float mA, float mB, float mN,   // m at planes zo-1, zo, zo+1
    float fA, float fB, float fN,
    int zflag,                      // -1: zo==0, +1: zo==DIM-1, 0: interior
    float gx_m, float gy_m, float gx_f, float gy_f,
    int km, int kf,
    float& o0, float& o1, float& o2)
{
    float mmean = sum_m / 27.0f;
    float fmean = sum_f / 27.0f;
    float var_m = sum_mm - 2.f*mmean*sum_m + 27.f*mmean*mmean;
    float var_f = sum_ff - 2.f*fmean*sum_f + 27.f*fmean*fmean;
    float var_mf = var_m * var_f;
    float cross = sum_mf - fmean*sum_m - mmean*sum_f + 27.f*mmean*fmean;
    float mmc = mB - mmean, fmc = fB - fmean;
    float factor = 2.f * cross / (var_mf + EPSF)
                   * (mmc - cross / (var_f*fmc + EPSF));
    float gzm = (zflag < 0) ? (mN - mB) : ((zflag > 0) ? (mB - mA) : 0.5f*(mN - mA));
    float gzf = (zflag < 0) ? (fN - fB) : ((zflag > 0) ? (fB - fA) : 0.5f*(fN - fA));
    float wm = km ? 1.f : 0.f, wf = kf ? 1.f : 0.f;
    float tgz = 0.5f*(gzm *wm + gzf *wf);
    float tgy = 0.5f*(gy_m*wm + gy_f*wf);
    float tgx = 0.5f*(gx_m*wm + gx_f*wf);
    o0 = -factor * tgz;
    o1 = -factor * tgy;
    o2 = -factor * tgx;
}

// raw rows of one z-plane for this wave's y (3 m-rows + 3 f-rows)
struct RawP { float4 mU, mC, mD, fU, fC, fD; };

__device__ __forceinline__ RawP load_planes(const float* __restrict__ M,
                                            const float* __restrict__ F,
                                            int zl, size_t yoff, bool yUok, bool yDok)
{
    const float4 z4 = make_float4(0.f, 0.f, 0.f, 0.f);
    RawP r; r.mU = z4; r.mC = z4; r.mD = z4; r.fU = z4; r.fC = z4; r.fD = z4;
    if ((unsigned)zl < (unsigned)DIM) {
        const float* pm = M + (size_t)zl * PLANE + yoff;
        const float* pf = F + (size_t)zl * PLANE + yoff;
        r.mC = *(const float4*)pm;  r.fC = *(const float4*)pf;
        if (yUok) { r.mU = *(const float4*)(pm - DIM); r.fU = *(const float4*)(pf - DIM); }
        if (yDok) { r.mD = *(const float4*)(pm + DIM); r.fD = *(const float4*)(pf + DIM); }
    }
    return r;
}

// pure compute half of the old 'ingest' — FP statements in identical order
__device__ __forceinline__ void ingest_compute(
    const RawP& r, int slot, int y,
    float4* mc, float4* fc,
    float4& Pm, float4& Pf, float4& Pmm, float4& Pff, float4& Pmf,
    float4& gxm, float4& gym, float4& gxf, float4& gyf)
{
    const float4 mU = r.mU, mC = r.mC, mD = r.mD;
    const float4 fU = r.fU, fC = r.fC, fD = r.fD;
    // y-sums per element (zero-padded SAME)
    float4 Cm  = add3(mU, mC, mD);
    float4 Cf  = add3(fU, fC, fD);
    float4 Cmm = prod3(mU, mU, mC, mC, mD, mD);
    float4 Cff = prod3(fU, fU, fC, fC, fD, fD);
    float4 Cmf = prod3(mU, fU, mC, fC, mD, fD);
    // x-sums (2 shuffles each)
    Pm  = xsum3(Cm);
    Pf  = xsum3(Cf);
    Pmm = xsum3(Cmm);
    Pff = xsum3(Cff);
    Pmf = xsum3(Cmf);
    mc[slot] = mC; fc[slot] = fC;
    // in-plane gradients at this plane (torch.gradient boundary rules)
    float mL = shlz(mC.w), mR = shrz(mC.x);
    float fL = shlz(fC.w), fR = shrz(fC.x);
    gxm = make_float4((threadIdx.x == 0)  ? (mC.y - mC.x) : 0.5f*(mC.y - mL),
                      0.5f*(mC.z - mC.x),
                      0.5f*(mC.w - mC.y),
                      (threadIdx.x == 63) ? (mC.w - mC.z) : 0.5f*(mR - mC.z));
    gxf = make_float4((threadIdx.x == 0)  ? (fC.y - fC.x) : 0.5f*(fC.y - fL),
                      0.5f*(fC.z - fC.x),
                      0.5f*(fC.w - fC.y),
                      (threadIdx.x == 63) ? (fC.w - fC.z) : 0.5f*(fR - fC.z));
    gym = (y == 0) ? sub4(mD, mC) : (y == DIM-1) ? sub4(mC, mU) : scl4(sub4(mD, mU), 0.5f);
    gyf = (y == 0) ? sub4(fD, fC) : (y == DIM-1) ? sub4(fC, fU) : scl4(sub4(fD, fU), 0.5f);
}

__global__ __launch_bounds__(64 * BY) void ncc_forces(
    const float* __restrict__ M, const float* __restrict__ F,
    const int* __restrict__ maskM, const int* __restrict__ maskF,
    float* __restrict__ out)
{
    const int y  = blockIdx.y * BY + threadIdx.y;
    const int z0 = blockIdx.z * CHUNK_Z;
    const int xb = threadIdx.x * 4;
    const bool yUok = (y > 0), yDok = (y < DIM - 1);
    const size_t yoff = (size_t)y * DIM + xb;

    float4 mc[3], fc[3];                 // center values z-ring
    float4 gxm_p, gym_p, gxf_p, gyf_p;   // in-plane grads at output plane

    // ---- prologue: issue everything before the first compute ----
    // masks for first output (zo = z0); consumed at s=2 (covered by 2 ingests)
    nivec4 km = __builtin_nontemporal_load((const nivec4*)(maskM + (size_t)z0 * PLANE + yoff));
    nivec4 kf = __builtin_nontemporal_load((const nivec4*)(maskF + (size_t)z0 * PLANE + yoff));
    RawP r0 = load_planes(M, F, z0 - 1, yoff, yUok, yDok);
    RawP r1 = load_planes(M, F, z0,     yoff, yUok, yDok);
    RawP rN = load_planes(M, F, z0 + 1, yoff, yUok, yDok);   // consumed at s=2

    // pair-sum z-accumulators: SA = P(old)+P(mid), SB = P(mid)
    float4 SAm, SAf, SAmm, SAff, SAmf, SBm, SBf, SBmm, SBff, SBmf;
    {
        float4 P0m, P0f, P0mm, P0ff, P0mf, d0, d1, d2, d3;
        ingest_compute(r0, 0, y, mc, fc, P0m, P0f, P0mm, P0ff, P0mf, d0, d1, d2, d3);
        float4 P1m, P1f, P1mm, P1ff, P1mf;
        ingest_compute(r1, 1, y, mc, fc, P1m, P1f, P1mm, P1ff, P1mf,
                       gxm_p, gym_p, gxf_p, gyf_p);
        // (P0+P1) — same association as add3's (a+b)+c first add
        SAm  = add2(P0m,  P1m );  SBm  = P1m;
        SAf  = add2(P0f,  P1f );  SBf  = P1f;
        SAmm = add2(P0mm, P1mm);  SBmm = P1mm;
        SAff = add2(P0ff, P1ff);  SBff = P1ff;
        SAmf = add2(P0mf, P1mf);  SBmf = P1mf;
    }

    #pragma unroll
    for (int s = 2; s < CHUNK_Z + 2; ++s) {
        const int i2 = s % 3, i1 = (s + 2) % 3, i0 = (s + 1) % 3;
        const int zo = z0 + s - 2;
        const int zflag = (zo == 0) ? -1 : ((zo == DIM - 1) ? 1 : 0);
        const size_t idx = (size_t)zo * PLANE + yoff;

        // 1) consume the raw loads issued one iteration ago
        float4 gxm, gym, gxf, gyf;
        float4 Pm2, Pf2, Pmm2, Pff2, Pmf2;
        ingest_compute(rN, i2, y, mc, fc, Pm2, Pf2, Pmm2, Pff2, Pmf2,
                       gxm, gym, gxf, gyf);

        // 2) issue NEXT plane's raw rows and NEXT output's masks now;
        //    they are consumed one iteration later (~a full ingest+pw1 of cover)
        nivec4 kmT, kfT;
        if (s < CHUNK_Z + 1) {
            rN  = load_planes(M, F, z0 + s, yoff, yUok, yDok);     // plane for s+1
            kmT = __builtin_nontemporal_load((const nivec4*)(maskM + idx + PLANE));
            kfT = __builtin_nontemporal_load((const nivec4*)(maskF + idx + PLANE));
        }

        // 3) z-sums: (P[z-2]+P[z-1]) + P[z] — identical association to add3
        float4 sm  = add2(SAm,  Pm2);
        float4 sf  = add2(SAf,  Pf2);
        float4 smm = add2(SAmm, Pmm2);
        float4 sff = add2(SAff, Pff2);
        float4 smf = add2(SAmf, Pmf2);

        float4 o0, o1, o2;
        pw1(sm.x, sf.x, smm.x, sff.x, smf.x, mc[i0].x, mc[i1].x, mc[i2].x,
            fc[i0].x, fc[i1].x, fc[i2].x, zflag, gxm_p.x, gym_p.x, gxf_p.x, gyf_p.x,
            km.x, kf.x, o0.x, o1.x, o2.x);
        pw1(sm.y, sf.y, smm.y, sff.y, smf.y, mc[i0].y, mc[i1].y, mc[i2].y,
            fc[i0].y, fc[i1].y, fc[i2].y, zflag, gxm_p.y, gym_p.y, gxf_p.y, gyf_p.y,
            km.y, kf.y, o0.y, o1.y, o2.y);
        pw1(sm.z, sf.z, smm.z, sff.z, smf.z, mc[i0].z, mc[i1].z, mc[i2].z,
            fc[i0].z, fc[i1].z, fc[i2].z, zflag, gxm_p.z, gym_p.z, gxf_p.z, gyf_p.z,
            km.z, kf.z, o0.z, o1.z, o2.z);
        pw1(sm.w, sf.w, smm.w, sff.w, smf.w, mc[i0].w, mc[i1].w, mc[i2].w,
            fc[i0].w, fc[i1].w, fc[i2].w, zflag, gxm_p.w, gym_p.w, gxf_p.w, gyf_p.w,
            km.w, kf.w, o0.w, o1.w, o2.w);

        ntstore4(out + idx,            o0);   // channel 0: d/dz
        ntstore4(out + NVOX + idx,     o1);   // channel 1: d/dy
        ntstore4(out + 2 * NVOX + idx, o2);   // channel 2: d/dx

        // 4) rotate accumulators / prefetch buffers
        SAm  = add2(SBm,  Pm2 );  SBm  = Pm2;
        SAf  = add2(SBf,  Pf2 );  SBf  = Pf2;
        SAmm = add2(SBmm, Pmm2);  SBmm = Pmm2;
        SAff = add2(SBff, Pff2);  SBff = Pff2;
        SAmf = add2(SBmf, Pmf2);  SBmf = Pmf2;
        gxm_p = gxm; gym_p = gym; gxf_p = gxf; gyf_p = gyf;
        if (s < CHUNK_Z + 1) { km = kmT; kf = kfT; }
    }
}

extern "C" void kernel_launch(void* const* d_in, const int* in_sizes, int n_in,
                              void* d_out, int out_size, void* d_ws, size_t ws_size,
                              hipStream_t stream) {
    const float* M  = (const float*)d_in[0];
    const float* F  = (const float*)d_in[1];
    const int* mm   = (const int*)d_in[2];
    const int* fm   = (const int*)d_in[3];
    float* out      = (float*)d_out;

    dim3 block(64, BY, 1);                       // one wave = one full x-row
    dim3 grid(1, DIM / BY, DIM / CHUNK_Z);       // 1 x 128 x 32 = 4096 blocks
    hipLaunchKernelGGL(ncc_forces, grid, block, 0, stream, M, F, mm, fm, out);
}